// Round 1
// baseline (1254.087 us; speedup 1.0000x reference)
//
#include <hip/hip_runtime.h>
#include <cmath>

// RobustAttention: blockwise (w=15) causal cosFormer linear attention.
// scores[l,j] = cos(theta_l - theta_j) * <relu(q_l), relu(k_j)>, j<=l
// out[l] = sum_j scores[l,j] * relu(v_j) / max(sum_j scores[l,j], 1e-6)
//
// Mapping: 1 thread per (tile, row l). 16 threads per tile (lane%16==15 idle).
// All 15 active lanes of a tile read identical k/v addresses -> intra-wave
// coalesced broadcast; every HBM byte is touched exactly once. No LDS.

namespace {

constexpr int W  = 15;      // block_size
constexpr int D  = 64;      // head dim
constexpr int CH = D / 4;   // float4 chunks per row
constexpr int TILES_PER_WG = 16;  // 16 tiles * 16 threads = 256

__global__ __launch_bounds__(256, 4)
void robust_attn_kernel(const float* __restrict__ q,
                        const float* __restrict__ k,
                        const float* __restrict__ v,
                        float* __restrict__ out,
                        int nblocks)
{
    const int l = threadIdx.x & 15;               // row within tile
    const int g = blockIdx.x * TILES_PER_WG + (threadIdx.x >> 4);  // tile id
    if (l >= W || g >= nblocks) return;

    const size_t blk_off = (size_t)g * (W * D);
    const float4* __restrict__ q4p = (const float4*)(q + blk_off + (size_t)l * D);
    const float4* __restrict__ k4p = (const float4*)(k + blk_off);
    const float4* __restrict__ v4p = (const float4*)(v + blk_off);
    float4* __restrict__ o4p       = (float4*)(out + blk_off + (size_t)l * D);

    // ---- load q row, relu, keep in registers (64 VGPRs, dead after phase 1)
    float4 qr[CH];
#pragma unroll
    for (int c = 0; c < CH; ++c) {
        float4 t = q4p[c];
        qr[c] = make_float4(fmaxf(t.x, 0.f), fmaxf(t.y, 0.f),
                            fmaxf(t.z, 0.f), fmaxf(t.w, 0.f));
    }

    // ---- phase 1: raw dots s[j] = <relu(q_l), relu(k_j)>
    float s[W];
#pragma unroll
    for (int j = 0; j < W; ++j) {
        float acc = 0.f;
#pragma unroll
        for (int c = 0; c < CH; ++c) {
            float4 kk = k4p[j * CH + c];
            acc += qr[c].x * fmaxf(kk.x, 0.f);
            acc += qr[c].y * fmaxf(kk.y, 0.f);
            acc += qr[c].z * fmaxf(kk.z, 0.f);
            acc += qr[c].w * fmaxf(kk.w, 0.f);
        }
        s[j] = acc;
    }

    // ---- cos reweight + causal mask + denom; fold 1/denom into weights
    const float step = 1.57079632679489662f / (float)W;  // (pi/2)/15
    float denom = 0.f;
#pragma unroll
    for (int j = 0; j < W; ++j) {
        float wcos = __cosf(step * (float)(l - j));
        float t = (j <= l) ? s[j] * wcos : 0.f;
        s[j] = t;
        denom += t;
    }
    const float inv = 1.f / fmaxf(denom, 1e-6f);
#pragma unroll
    for (int j = 0; j < W; ++j) s[j] *= inv;

    // ---- phase 2: out[l] = sum_j s[j] * relu(v_j)
#pragma unroll
    for (int c = 0; c < CH; ++c) {
        float ax = 0.f, ay = 0.f, az = 0.f, aw = 0.f;
#pragma unroll
        for (int j = 0; j < W; ++j) {
            float4 vv = v4p[j * CH + c];
            ax += s[j] * fmaxf(vv.x, 0.f);
            ay += s[j] * fmaxf(vv.y, 0.f);
            az += s[j] * fmaxf(vv.z, 0.f);
            aw += s[j] * fmaxf(vv.w, 0.f);
        }
        o4p[c] = make_float4(ax, ay, az, aw);
    }
}

}  // namespace

extern "C" void kernel_launch(void* const* d_in, const int* in_sizes, int n_in,
                              void* d_out, int out_size, void* d_ws, size_t ws_size,
                              hipStream_t stream) {
    const float* q = (const float*)d_in[0];
    const float* k = (const float*)d_in[1];
    const float* v = (const float*)d_in[2];
    float* out = (float*)d_out;

    const int total   = in_sizes[0];          // B*H*L*D
    const int nblocks = total / (W * D);      // 20480 for the bench shape
    const int wgs     = (nblocks + TILES_PER_WG - 1) / TILES_PER_WG;

    robust_attn_kernel<<<wgs, 256, 0, stream>>>(q, k, v, out, nblocks);
}

// Round 2
// 1131.397 us; speedup vs baseline: 1.1084x; 1.1084x over previous
//
#include <hip/hip_runtime.h>

// RobustAttention: blockwise (w=15) causal cosFormer linear attention.
// scores[l,j] = cos(theta_l - theta_j) * <relu(q_l), relu(k_j)>, j<=l
// out[l] = sum_j scores[l,j] * relu(v_j) / max(sum_j scores[l,j], 1e-6)
//
// R2: two-phase with LDS weight buffer.
//   Phase 1: thread = (tile, row l). Computes normalized causal weights
//            s[l][0..14] and writes them to LDS (stride 17 to dodge banks).
//            k reads are wave-broadcast (16 lanes same addr), q reads are
//            per-lane full-line reads -> fetch-efficient.
//   Phase 2: thread = (tile, d-chunk d16). v loads and out stores are fully
//            coalesced (16 lanes x float4 = 256 B contiguous). This kills
//            the R1 partial-line-store RMW disaster (WRITE 1.33 GB -> 80 MB).

namespace {

constexpr int W  = 15;      // block_size
constexpr int D  = 64;      // head dim
constexpr int CH = D / 4;   // float4 chunks per row
constexpr int TILES = 16;   // tiles per workgroup (256 threads)
constexpr int SSTRIDE = 17; // LDS row stride (floats), padded vs 15/16

__global__ __launch_bounds__(256, 4)
void robust_attn_kernel(const float* __restrict__ q,
                        const float* __restrict__ k,
                        const float* __restrict__ v,
                        float* __restrict__ out,
                        int nblocks)
{
    __shared__ float s_lds[TILES * W * SSTRIDE];

    const int lane = threadIdx.x & 15;            // row l (ph1) / d-chunk (ph2)
    const int t    = threadIdx.x >> 4;            // tile within WG
    const int g    = blockIdx.x * TILES + t;      // global tile id
    const bool active = (g < nblocks);

    // ---------------- phase 1: weights ----------------
    if (active && lane < W) {
        const int l = lane;
        const float4* __restrict__ q4 =
            (const float4*)q + (size_t)g * (W * CH) + (size_t)l * CH;
        const float4* __restrict__ k4 =
            (const float4*)k + (size_t)g * (W * CH);

        float4 qr[CH];
#pragma unroll
        for (int c = 0; c < CH; ++c) {
            float4 tq = q4[c];
            qr[c] = make_float4(fmaxf(tq.x, 0.f), fmaxf(tq.y, 0.f),
                                fmaxf(tq.z, 0.f), fmaxf(tq.w, 0.f));
        }

        float s[W];
#pragma unroll
        for (int j = 0; j < W; ++j) {
            float acc = 0.f;
#pragma unroll
            for (int c = 0; c < CH; ++c) {
                float4 kk = k4[j * CH + c];
                acc += qr[c].x * fmaxf(kk.x, 0.f);
                acc += qr[c].y * fmaxf(kk.y, 0.f);
                acc += qr[c].z * fmaxf(kk.z, 0.f);
                acc += qr[c].w * fmaxf(kk.w, 0.f);
            }
            s[j] = acc;
        }

        const float step = 1.57079632679489662f / (float)W;  // (pi/2)/15
        float denom = 0.f;
#pragma unroll
        for (int j = 0; j < W; ++j) {
            float wcos = __cosf(step * (float)(l - j));
            float tv = (j <= l) ? s[j] * wcos : 0.f;
            s[j] = tv;
            denom += tv;
        }
        const float inv = 1.f / fmaxf(denom, 1e-6f);

        float* __restrict__ srow = &s_lds[(t * W + l) * SSTRIDE];
#pragma unroll
        for (int j = 0; j < W; ++j) srow[j] = s[j] * inv;
    }

    __syncthreads();

    // ---------------- phase 2: out = S @ relu(v), coalesced ----------------
    if (active) {
        const float4* __restrict__ v4 =
            (const float4*)v + (size_t)g * (W * CH) + lane;
        float4* __restrict__ o4 =
            (float4*)out + (size_t)g * (W * CH) + lane;
        const float* __restrict__ sbase = &s_lds[t * W * SSTRIDE];

        float4 vv[W];
#pragma unroll
        for (int j = 0; j < W; ++j) {
            float4 tv = v4[j * CH];
            vv[j] = make_float4(fmaxf(tv.x, 0.f), fmaxf(tv.y, 0.f),
                                fmaxf(tv.z, 0.f), fmaxf(tv.w, 0.f));
        }

#pragma unroll
        for (int l = 0; l < W; ++l) {
            float ax = 0.f, ay = 0.f, az = 0.f, aw = 0.f;
#pragma unroll
            for (int j = 0; j <= l; ++j) {      // causal: s[l][j]=0 for j>l
                const float w = sbase[l * SSTRIDE + j];
                ax += w * vv[j].x;
                ay += w * vv[j].y;
                az += w * vv[j].z;
                aw += w * vv[j].w;
            }
            o4[l * CH] = make_float4(ax, ay, az, aw);
        }
    }
}

}  // namespace

extern "C" void kernel_launch(void* const* d_in, const int* in_sizes, int n_in,
                              void* d_out, int out_size, void* d_ws, size_t ws_size,
                              hipStream_t stream) {
    const float* q = (const float*)d_in[0];
    const float* k = (const float*)d_in[1];
    const float* v = (const float*)d_in[2];
    float* out = (float*)d_out;

    const int total   = in_sizes[0];          // B*H*L*D
    const int nblocks = total / (W * D);      // 20480 for the bench shape
    const int wgs     = (nblocks + TILES - 1) / TILES;

    robust_attn_kernel<<<wgs, 256, 0, stream>>>(q, k, v, out, nblocks);
}

// Round 3
// 255.668 us; speedup vs baseline: 4.9051x; 4.4253x over previous
//
#include <hip/hip_runtime.h>

// RobustAttention: blockwise (w=15) causal cosFormer linear attention.
// scores[l,j] = cos(th_l - th_j) * <relu(q_l), relu(k_j)>, j<=l
// out[l] = sum_j scores[l,j] * relu(v_j) / max(sum_j scores[l,j], 1e-6)
//
// R3: kill the request-granularity bottleneck.
//  - relu(k) staged to LDS via wave-wide coalesced float4 loads (1 KB/instr);
//    phase-1 reads k from LDS (15-lane broadcast = free, tiles bank-skewed
//    by the +1-float4 tile stride).
//  - scores never touch LDS: phase-1 lane (t,l) holds row-l weights in regs,
//    phase-2 lanes fetch them with __shfl. Single __syncthreads total.
//  - q: per-lane sequential 256-B row (L1-line resident across c-loop).
//  - v loads / out stores: coalesced 256-B chunks per tile (as R2).

namespace {

constexpr int W        = 15;            // block_size (rows per tile)
constexpr int CH       = 16;            // float4 per row (D=64)
constexpr int TILE4    = W * CH;        // 240 float4 per tile
constexpr int TPG      = 16;            // tiles per workgroup
constexpr int KSTRIDE4 = TILE4 + 1;     // 241: LDS tile stride, bank skew
constexpr int NTHREADS = 256;

__global__ __launch_bounds__(NTHREADS, 2)
void robust_attn_kernel(const float4* __restrict__ q4,
                        const float4* __restrict__ k4,
                        const float4* __restrict__ v4,
                        float4* __restrict__ o4,
                        int nblocks)
{
    __shared__ float4 k_lds[TPG * KSTRIDE4];   // 61,696 B

    const int tid  = threadIdx.x;
    const int lane = tid & 15;                 // row l (ph1) / d-chunk (ph2)
    const int t    = tid >> 4;                 // tile within WG
    const int g0   = blockIdx.x * TPG;
    const int g    = g0 + t;

    // ---------- stage relu(k) into LDS: 64 lanes x 16 B contiguous ----------
    {
        const size_t base  = (size_t)g0 * TILE4;
        const bool   full  = (g0 + TPG <= nblocks);
        const int    limit = nblocks * TILE4 - (int)base;
#pragma unroll
        for (int r = 0; r < (TPG * TILE4) / NTHREADS; ++r) {   // 15 iters
            const int idx = tid + r * NTHREADS;
            float4 kk = make_float4(0.f, 0.f, 0.f, 0.f);
            if (full || idx < limit) kk = k4[base + idx];
            const int tt  = idx / TILE4;
            const int pos = idx - tt * TILE4;
            k_lds[tt * KSTRIDE4 + pos] =
                make_float4(fmaxf(kk.x, 0.f), fmaxf(kk.y, 0.f),
                            fmaxf(kk.z, 0.f), fmaxf(kk.w, 0.f));
        }
    }
    __syncthreads();

    // ---------- phase 1: normalized causal cos-weights, in registers -------
    float s[W];
#pragma unroll
    for (int j = 0; j < W; ++j) s[j] = 0.f;

    if (g < nblocks && lane < W) {
        const int l = lane;
        const float4* __restrict__ qp = q4 + (size_t)g * TILE4 + l * CH;

        float4 qr[CH];
#pragma unroll
        for (int c = 0; c < CH; ++c) {
            float4 tq = qp[c];
            qr[c] = make_float4(fmaxf(tq.x, 0.f), fmaxf(tq.y, 0.f),
                                fmaxf(tq.z, 0.f), fmaxf(tq.w, 0.f));
        }

        const float4* __restrict__ kl = &k_lds[t * KSTRIDE4];
#pragma unroll
        for (int j = 0; j < W; ++j) {
            float acc = 0.f;
#pragma unroll
            for (int c = 0; c < CH; ++c) {
                float4 kk = kl[j * CH + c];
                acc = fmaf(qr[c].x, kk.x, acc);
                acc = fmaf(qr[c].y, kk.y, acc);
                acc = fmaf(qr[c].z, kk.z, acc);
                acc = fmaf(qr[c].w, kk.w, acc);
            }
            s[j] = acc;
        }

        const float step = 1.57079632679489662f / (float)W;  // (pi/2)/15
        float denom = 0.f;
#pragma unroll
        for (int j = 0; j < W; ++j) {
            float wc = __cosf(step * (float)(l - j));
            float tv = (j <= l) ? s[j] * wc : 0.f;
            s[j] = tv;
            denom += tv;
        }
        const float inv = 1.f / fmaxf(denom, 1e-6f);
#pragma unroll
        for (int j = 0; j < W; ++j) s[j] *= inv;
    }

    // ---------- phase 2: out = S @ relu(v); weights via wave shuffle -------
    if (g < nblocks) {
        const float4* __restrict__ vp = v4 + (size_t)g * TILE4 + lane;
        float4* __restrict__ op       = o4 + (size_t)g * TILE4 + lane;

        float4 vv[W];
#pragma unroll
        for (int j = 0; j < W; ++j) {
            float4 tv = vp[j * CH];
            vv[j] = make_float4(fmaxf(tv.x, 0.f), fmaxf(tv.y, 0.f),
                                fmaxf(tv.z, 0.f), fmaxf(tv.w, 0.f));
        }

        const int tbase = tid & 48;   // tile base lane within the wave
#pragma unroll
        for (int l = 0; l < W; ++l) {
            float ax = 0.f, ay = 0.f, az = 0.f, aw = 0.f;
#pragma unroll
            for (int j = 0; j <= l; ++j) {     // causal
                const float w = __shfl(s[j], tbase + l, 64);
                ax = fmaf(w, vv[j].x, ax);
                ay = fmaf(w, vv[j].y, ay);
                az = fmaf(w, vv[j].z, az);
                aw = fmaf(w, vv[j].w, aw);
            }
            op[l * CH] = make_float4(ax, ay, az, aw);
        }
    }
}

}  // namespace

extern "C" void kernel_launch(void* const* d_in, const int* in_sizes, int n_in,
                              void* d_out, int out_size, void* d_ws, size_t ws_size,
                              hipStream_t stream) {
    const float4* q = (const float4*)d_in[0];
    const float4* k = (const float4*)d_in[1];
    const float4* v = (const float4*)d_in[2];
    float4* out = (float4*)d_out;

    const int total   = in_sizes[0];           // B*H*L*D
    const int nblocks = total / (W * CH * 4);  // 20480 for the bench shape
    const int wgs     = (nblocks + TPG - 1) / TPG;

    robust_attn_kernel<<<wgs, NTHREADS, 0, stream>>>(q, k, v, out, nblocks);
}